// Round 10
// baseline (559.027 us; speedup 1.0000x reference)
//
#include <hip/hip_runtime.h>
#include <hip/hip_bf16.h>

typedef __attribute__((ext_vector_type(8))) short bf16x8;   // 8 bf16 in 4 VGPRs (MFMA A/B frag)
typedef __attribute__((ext_vector_type(4))) float f32x4;    // MFMA C/D frag

__device__ __forceinline__ unsigned short f2bf(float f) {   // RNE fp32->bf16
    unsigned u = __float_as_uint(f);
    u += 0x7fff + ((u >> 16) & 1);
    return (unsigned short)(u >> 16);
}
__device__ __forceinline__ float bf2f(unsigned short s) {
    return __uint_as_float(((unsigned)s) << 16);
}
__device__ __forceinline__ float4 bf4(ushort4 v) {
    return make_float4(bf2f(v.x), bf2f(v.y), bf2f(v.z), bf2f(v.w));
}

#define GL2LDS16(g, l) __builtin_amdgcn_global_load_lds(                      \
        (const __attribute__((address_space(1))) void*)(g),                   \
        (__attribute__((address_space(3))) void*)(l), 16, 0, 0)

// ---------------- fused setup: degree count + weight transposes + x->bf16 ----------------

__global__ __launch_bounds__(256) void fused_misc_kernel(
        const int* __restrict__ dst, int* __restrict__ cnt, int e,
        const float* __restrict__ Wa, unsigned short* __restrict__ Ta, int Ka,
        const float* __restrict__ Wb, unsigned short* __restrict__ Tb,
        const float* __restrict__ Wc, unsigned short* __restrict__ Tc,
        const float* __restrict__ x, unsigned short* __restrict__ xb, int n4,
        int CB, int TB) {
    int b = blockIdx.x;
    if (b < CB) {
        int i = b * 256 + threadIdx.x;
        if (i < e) atomicAdd(&cnt[dst[i]], 1);
    } else if (b < CB + TB) {
        int i = (b - CB) * 256 + threadIdx.x;
        int na = Ka * 256, nb = 256 * 256;
        if (i < na) {
            int k = i >> 8, n = i & 255;
            Ta[(size_t)n * Ka + k] = f2bf(Wa[i]);
        } else if (i < na + nb) {
            int j = i - na; int k = j >> 8, n = j & 255;
            Tb[(size_t)n * 256 + k] = f2bf(Wb[j]);
        } else if (i < na + 2 * nb) {
            int j = i - na - nb; int k = j >> 8, n = j & 255;
            Tc[(size_t)n * 256 + k] = f2bf(Wc[j]);
        }
    } else {
        int i = (b - CB - TB) * 256 + threadIdx.x;
        if (i < n4) {
            float4 v = ((const float4*)x)[i];
            ushort4 o;
            o.x = f2bf(v.x); o.y = f2bf(v.y); o.z = f2bf(v.z); o.w = f2bf(v.w);
            ((ushort4*)xb)[i] = o;
        }
    }
}

// ---------------- CSR scan (3-stage) ----------------

__global__ __launch_bounds__(256) void block_sum_kernel(const int* __restrict__ cnt,
                                                        int* __restrict__ bsums, int n) {
    int tid = threadIdx.x;
    int i = blockIdx.x * 256 + tid;
    int v = (i < n) ? cnt[i] : 0;
    #pragma unroll
    for (int off = 32; off > 0; off >>= 1) v += __shfl_down(v, off);
    __shared__ int ws[4];
    if ((tid & 63) == 0) ws[tid >> 6] = v;
    __syncthreads();
    if (tid == 0) bsums[blockIdx.x] = ws[0] + ws[1] + ws[2] + ws[3];
}

__global__ __launch_bounds__(256) void bsum_scan_kernel(int* __restrict__ bsums, int nb) {
    int tid = threadIdx.x;
    int lane = tid & 63, wid = tid >> 6;
    int v = (tid < nb) ? bsums[tid] : 0;
    int s = v;
    #pragma unroll
    for (int off = 1; off < 64; off <<= 1) {
        int t = __shfl_up(s, off);
        if (lane >= off) s += t;
    }
    __shared__ int ws[4];
    if (lane == 63) ws[wid] = s;
    __syncthreads();
    int wo = 0;
    #pragma unroll
    for (int k = 0; k < 4; ++k) wo += (k < wid) ? ws[k] : 0;
    if (tid < nb) bsums[tid] = wo + s - v;   // exclusive
}

__global__ __launch_bounds__(256) void scatter_scan_kernel(const int* __restrict__ cnt,
                                                           const int* __restrict__ bsums,
                                                           int* __restrict__ offsets,
                                                           int* __restrict__ cursor,
                                                           float* __restrict__ dinv, int n) {
    int tid = threadIdx.x;
    int lane = tid & 63, wid = tid >> 6;
    int i = blockIdx.x * 256 + tid;
    int v = (i < n) ? cnt[i] : 0;
    int s = v;
    #pragma unroll
    for (int off = 1; off < 64; off <<= 1) {
        int t = __shfl_up(s, off);
        if (lane >= off) s += t;
    }
    __shared__ int ws[4];
    if (lane == 63) ws[wid] = s;
    __syncthreads();
    int wo = 0;
    #pragma unroll
    for (int k = 0; k < 4; ++k) wo += (k < wid) ? ws[k] : 0;
    int excl = bsums[blockIdx.x] + wo + s - v;
    if (i <= n) { offsets[i] = excl; }
    if (i < n) {
        cursor[i] = excl;
        dinv[i] = rsqrtf((float)v + 1.0f);
    }
}

__global__ void fill_kernel(const int* __restrict__ src, const int* __restrict__ dst,
                            int* __restrict__ cursor, int* __restrict__ csr, int e) {
    int i = blockIdx.x * blockDim.x + threadIdx.x;
    if (i < e) {
        int p = atomicAdd(&cursor[dst[i]], 1);
        csr[p] = src[i];
    }
}

// ---------------- bf16 MFMA GEMM: C = A[M,K] @ W[K,256], BK=64 ----------------
// MODE 0: +bias[col], row-major C[M][256]
// MODE 1: *dinv[row], slice-major C[(col/32)][M][32] (64B/node slices, L2-local gather)

template <int MODE>
__global__ __launch_bounds__(256) void gemm_bf16(const unsigned short* __restrict__ A,
                                                 const unsigned short* __restrict__ Wt,
                                                 const float* __restrict__ aux,
                                                 unsigned short* __restrict__ C,
                                                 int M, int K) {
    __shared__ unsigned short As[128 * 64];   // [row][k] 16 KB
    __shared__ unsigned short Bs[128 * 64];   // [col][k] 16 KB
    const int tid  = threadIdx.x;
    const int lane = tid & 63;
    const int w    = tid >> 6;
    const int wr   = w >> 1, wc = w & 1;
    const int row0 = blockIdx.x * 128;
    const int col0 = blockIdx.y * 128;
    const int mlane = lane & 15, quad = lane >> 4;

    f32x4 acc[4][4];
    #pragma unroll
    for (int i = 0; i < 4; ++i)
        #pragma unroll
        for (int j = 0; j < 4; ++j) acc[i][j] = f32x4{0.f, 0.f, 0.f, 0.f};

    const unsigned short* gA[4]; const unsigned short* gB[4];
    unsigned short* lA[4]; unsigned short* lB[4];
    #pragma unroll
    for (int p = 0; p < 4; ++p) {
        int cid = (p * 4 + w) * 64 + lane;
        int row = cid >> 3, slot = cid & 7;
        int rowA = row0 + row; if (rowA >= M) rowA = M - 1;
        gA[p] = A + (size_t)rowA * K + slot * 8;
        gB[p] = Wt + (size_t)(col0 + row) * K + slot * 8;
        lA[p] = &As[((p * 4 + w) * 64) * 8];
        lB[p] = &Bs[((p * 4 + w) * 64) * 8];
    }

    for (int k0 = 0; k0 < K; k0 += 64) {
        #pragma unroll
        for (int p = 0; p < 4; ++p) GL2LDS16(gA[p] + k0, lA[p]);
        #pragma unroll
        for (int p = 0; p < 4; ++p) GL2LDS16(gB[p] + k0, lB[p]);
        __syncthreads();
        #pragma unroll
        for (int ks = 0; ks < 2; ++ks) {
            bf16x8 af[4], bfv[4];
            #pragma unroll
            for (int i = 0; i < 4; ++i)
                af[i] = *(const bf16x8*)&As[(wr * 64 + i * 16 + mlane) * 64 + ks * 32 + quad * 8];
            #pragma unroll
            for (int j = 0; j < 4; ++j)
                bfv[j] = *(const bf16x8*)&Bs[(wc * 64 + j * 16 + mlane) * 64 + ks * 32 + quad * 8];
            #pragma unroll
            for (int i = 0; i < 4; ++i)
                #pragma unroll
                for (int j = 0; j < 4; ++j)
                    acc[i][j] = __builtin_amdgcn_mfma_f32_16x16x32_bf16(af[i], bfv[j], acc[i][j], 0, 0, 0);
        }
        __syncthreads();
    }

    float bj[4];
    if (MODE == 0) {
        #pragma unroll
        for (int j = 0; j < 4; ++j) bj[j] = aux[col0 + wc * 64 + j * 16 + mlane];
    }
    #pragma unroll
    for (int i = 0; i < 4; ++i) {
        #pragma unroll
        for (int r = 0; r < 4; ++r) {
            int grow = row0 + wr * 64 + i * 16 + quad * 4 + r;
            if (grow < M) {
                float d = (MODE == 1) ? aux[grow] : 0.f;
                #pragma unroll
                for (int j = 0; j < 4; ++j) {
                    int gcol = col0 + wc * 64 + j * 16 + mlane;
                    float v = acc[i][j][r];
                    if (MODE == 0) {
                        C[(size_t)grow * 256 + gcol] = f2bf(v + bj[j]);
                    } else {
                        C[((size_t)(gcol >> 5) * M + grow) * 32 + (gcol & 31)] = f2bf(v * d);
                    }
                }
            }
        }
    }
}

// ---------------- aggregation v3: sliced + 8-edges-per-instruction ----------------
// hsS [slice][node][32ch]; slice = blockIdx&7 (XCD round-robin -> L2-resident slice).
// One wave per (node, slice): lane = edge_slot(es,8) x chan_group(cg,8).
// Gather: 8 edges x 8 B (ushort4) = 512 B per instruction; no cross-lane index ops.
// 2x unrolled (16 edges in flight). shfl_xor(8/16/32) folds edge slots at the end.

__global__ __launch_bounds__(256) void agg_kernel(const unsigned short* __restrict__ hsS,
                                                  const int* __restrict__ offsets,
                                                  const int* __restrict__ csr,
                                                  const float* __restrict__ dinv,
                                                  const float* __restrict__ bias,
                                                  unsigned short* __restrict__ out, int n) {
    int slice = blockIdx.x & 7;
    int node = (blockIdx.x >> 3) * 4 + (threadIdx.x >> 6);
    if (node >= n) return;
    int lane = threadIdx.x & 63;
    int es = lane >> 3;    // edge slot 0..7
    int cg = lane & 7;     // channel 4-group: ch [cg*4, cg*4+4)
    const unsigned short* base = hsS + (size_t)slice * n * 32;
    int beg = offsets[node], end = offsets[node + 1];

    float4 acc = make_float4(0.f, 0.f, 0.f, 0.f);
    {   // self-loop row: keep on es==0 lanes only
        ushort4 sv = ((const ushort4*)(base + (size_t)node * 32))[cg];
        float4 f = bf4(sv);
        if (es == 0) acc = f;
    }

    int e = beg;
    for (; e + 16 <= end; e += 16) {   // two independent 8-edge chains
        int i0 = csr[e + es];
        int i1 = csr[e + 8 + es];
        ushort4 v0 = ((const ushort4*)(base + (size_t)i0 * 32))[cg];
        ushort4 v1 = ((const ushort4*)(base + (size_t)i1 * 32))[cg];
        float4 f0 = bf4(v0), f1 = bf4(v1);
        acc.x += f0.x + f1.x; acc.y += f0.y + f1.y;
        acc.z += f0.z + f1.z; acc.w += f0.w + f1.w;
    }
    if (e < end) {   // tail chunk (<16 edges)
        int ee = e + es;
        int cl = (ee < end) ? ee : (end - 1);
        int i0 = csr[cl];
        ushort4 v0 = ((const ushort4*)(base + (size_t)i0 * 32))[cg];
        float4 f0 = bf4(v0);
        if (ee < end) {
            acc.x += f0.x; acc.y += f0.y; acc.z += f0.z; acc.w += f0.w;
        }
        int ee1 = e + 8 + es;
        if (ee1 < end) {
            int i1 = csr[ee1];
            ushort4 v1 = ((const ushort4*)(base + (size_t)i1 * 32))[cg];
            float4 f1 = bf4(v1);
            acc.x += f1.x; acc.y += f1.y; acc.z += f1.z; acc.w += f1.w;
        }
    }

    // fold the 8 edge slots (lane bits 3..5)
    #pragma unroll
    for (int m = 8; m <= 32; m <<= 1) {
        acc.x += __shfl_xor(acc.x, m);
        acc.y += __shfl_xor(acc.y, m);
        acc.z += __shfl_xor(acc.z, m);
        acc.w += __shfl_xor(acc.w, m);
    }

    if (es == 0) {
        float d = dinv[node];
        float4 b = ((const float4*)bias)[slice * 8 + cg];
        ushort4 r;
        r.x = f2bf(fmaxf(fmaf(acc.x, d, b.x), 0.f));
        r.y = f2bf(fmaxf(fmaf(acc.y, d, b.y), 0.f));
        r.z = f2bf(fmaxf(fmaf(acc.z, d, b.z), 0.f));
        r.w = f2bf(fmaxf(fmaf(acc.w, d, b.w), 0.f));
        ((ushort4*)(out + (size_t)node * 256 + slice * 32))[cg] = r;
    }
}

// ---------------- pooling (known-good split) ----------------

__global__ __launch_bounds__(256) void pool_partial_kernel(const unsigned short* __restrict__ h,
                                                           const int* __restrict__ batch,
                                                           float* __restrict__ sums,
                                                           int* __restrict__ counts,
                                                           int n, int chunk) {
    int beg = blockIdx.x * chunk;
    int end = beg + chunk; if (end > n) end = n;
    if (beg >= end) return;
    int c = threadIdx.x;
    int curg = batch[beg];
    float acc = 0.f;
    int runlen = 0;
    for (int i = beg; i < end; ++i) {
        int g = batch[i];
        if (g != curg) {
            atomicAdd(&sums[(size_t)curg * 256 + c], acc);
            if (c == 0) atomicAdd(&counts[curg], runlen);
            acc = 0.f; runlen = 0; curg = g;
        }
        acc += bf2f(h[(size_t)i * 256 + c]);
        ++runlen;
    }
    atomicAdd(&sums[(size_t)curg * 256 + c], acc);
    if (c == 0) atomicAdd(&counts[curg], runlen);
}

__global__ __launch_bounds__(256) void pool_final_kernel(const float* __restrict__ sums,
                                                         const int* __restrict__ counts,
                                                         const float* __restrict__ Wout,
                                                         const float* __restrict__ bout,
                                                         float* __restrict__ out) {
    __shared__ float pl[256];
    int g = blockIdx.x;
    int c = threadIdx.x;
    int cnt = counts[g];
    pl[c] = sums[(size_t)g * 256 + c] / (float)(cnt > 0 ? cnt : 1);
    __syncthreads();
    if (c < 16) {
        float o = bout[c];
        #pragma unroll 4
        for (int k = 0; k < 256; ++k) o = fmaf(pl[k], Wout[k * 16 + c], o);
        out[g * 16 + c] = o;
    }
}

// ---------------- launch ----------------

extern "C" void kernel_launch(void* const* d_in, const int* in_sizes, int n_in,
                              void* d_out, int out_size, void* d_ws, size_t ws_size,
                              hipStream_t stream) {
    const float* x     = (const float*)d_in[0];
    const int*   ei    = (const int*)d_in[1];
    const int*   batch = (const int*)d_in[2];
    const float* W_in  = (const float*)d_in[3];
    const float* b_in  = (const float*)d_in[4];
    const float* W1    = (const float*)d_in[5];
    const float* b1    = (const float*)d_in[6];
    const float* W2    = (const float*)d_in[7];
    const float* b2    = (const float*)d_in[8];
    const float* Wout  = (const float*)d_in[9];
    const float* bout  = (const float*)d_in[10];

    const int E = in_sizes[1] / 2;
    const int N = in_sizes[2];
    const int IN_DIM = in_sizes[0] / N;   // 128
    const int G = 128;
    const int* src = ei;
    const int* dst = ei + E;

    char* ws = (char*)d_ws;
    size_t off = 0;
    auto alloc = [&](size_t bytes) { size_t p = off; off += (bytes + 255) & ~(size_t)255; return p; };
    unsigned short* bufA = (unsigned short*)(ws + alloc((size_t)N * 256 * 2));
    unsigned short* bufB = (unsigned short*)(ws + alloc((size_t)N * 256 * 2));
    unsigned short* xb   = (unsigned short*)(ws + alloc((size_t)N * IN_DIM * 2));
    unsigned short* WtIn = (unsigned short*)(ws + alloc((size_t)IN_DIM * 256 * 2));
    unsigned short* Wt1  = (unsigned short*)(ws + alloc((size_t)256 * 256 * 2));
    unsigned short* Wt2  = (unsigned short*)(ws + alloc((size_t)256 * 256 * 2));
    size_t zbeg = off;
    int*   deg_cnt = (int*)(ws + alloc((size_t)N * 4));
    float* sums    = (float*)(ws + alloc((size_t)G * 256 * 4));
    int*   counts  = (int*)(ws + alloc((size_t)G * 4));
    size_t zend = off;
    float* dinv    = (float*)(ws + alloc((size_t)N * 4));
    int*   offsets = (int*)(ws + alloc((size_t)(N + 1) * 4));
    int*   cursor  = (int*)(ws + alloc((size_t)N * 4));
    int*   csr     = (int*)(ws + alloc((size_t)E * 4));
    int*   bsums   = (int*)(ws + alloc((size_t)256 * 4));
    (void)ws_size;

    const int NB  = (N + 255) / 256;
    const int NB1 = (N + 1 + 255) / 256;
    const int CB  = (E + 255) / 256;
    const int TB  = (IN_DIM * 256 + 2 * 256 * 256 + 255) / 256;
    const int XB  = (N * IN_DIM / 4 + 255) / 256;

    hipMemsetAsync(ws + zbeg, 0, zend - zbeg, stream);
    fused_misc_kernel<<<CB + TB + XB, 256, 0, stream>>>(
        dst, deg_cnt, E, W_in, WtIn, IN_DIM, W1, Wt1, W2, Wt2,
        x, xb, N * IN_DIM / 4, CB, TB);
    block_sum_kernel<<<NB, 256, 0, stream>>>(deg_cnt, bsums, N);
    bsum_scan_kernel<<<1, 256, 0, stream>>>(bsums, NB);
    scatter_scan_kernel<<<NB1, 256, 0, stream>>>(deg_cnt, bsums, offsets, cursor, dinv, N);
    fill_kernel<<<(E + 255) / 256, 256, 0, stream>>>(src, dst, cursor, csr, E);

    dim3 gg((N + 127) / 128, 2);
    dim3 ag(((N + 3) / 4) * 8);   // 8 slices x ceil(N/4) node-quads; slice = blockIdx & 7
    gemm_bf16<0><<<gg, 256, 0, stream>>>(xb, WtIn, b_in, bufA, N, IN_DIM);
    gemm_bf16<1><<<gg, 256, 0, stream>>>(bufA, Wt1, dinv, bufB, N, 256);   // bufB sliced
    agg_kernel<<<ag, 256, 0, stream>>>(bufB, offsets, csr, dinv, b1, bufA, N);
    gemm_bf16<1><<<gg, 256, 0, stream>>>(bufA, Wt2, dinv, bufB, N, 256);   // bufB sliced
    agg_kernel<<<ag, 256, 0, stream>>>(bufB, offsets, csr, dinv, b2, bufA, N);

    const int PBLOCKS = 400;
    int chunk = (N + PBLOCKS - 1) / PBLOCKS;
    pool_partial_kernel<<<PBLOCKS, 256, 0, stream>>>(bufA, batch, sums, counts, N, chunk);
    pool_final_kernel<<<G, 256, 0, stream>>>(sums, counts, Wout, bout, (float*)d_out);
}

// Round 11
// 404.034 us; speedup vs baseline: 1.3836x; 1.3836x over previous
//
#include <hip/hip_runtime.h>
#include <hip/hip_bf16.h>

typedef __attribute__((ext_vector_type(8))) short bf16x8;   // 8 bf16 in 4 VGPRs (MFMA A/B frag)
typedef __attribute__((ext_vector_type(4))) float f32x4;    // MFMA C/D frag

__device__ __forceinline__ unsigned short f2bf(float f) {   // RNE fp32->bf16
    unsigned u = __float_as_uint(f);
    u += 0x7fff + ((u >> 16) & 1);
    return (unsigned short)(u >> 16);
}
__device__ __forceinline__ float bf2f(unsigned short s) {
    return __uint_as_float(((unsigned)s) << 16);
}

#define GL2LDS16(g, l) __builtin_amdgcn_global_load_lds(                      \
        (const __attribute__((address_space(1))) void*)(g),                   \
        (__attribute__((address_space(3))) void*)(l), 16, 0, 0)

// ---------------- fused setup: degree count + weight transposes + x->bf16 ----------------

__global__ __launch_bounds__(256) void fused_misc_kernel(
        const int* __restrict__ dst, int* __restrict__ cnt, int e,
        const float* __restrict__ Wa, unsigned short* __restrict__ Ta, int Ka,
        const float* __restrict__ Wb, unsigned short* __restrict__ Tb,
        const float* __restrict__ Wc, unsigned short* __restrict__ Tc,
        const float* __restrict__ x, unsigned short* __restrict__ xb, int n4,
        int CB, int TB) {
    int b = blockIdx.x;
    if (b < CB) {
        int i = b * 256 + threadIdx.x;
        if (i < e) atomicAdd(&cnt[dst[i]], 1);
    } else if (b < CB + TB) {
        int i = (b - CB) * 256 + threadIdx.x;
        int na = Ka * 256, nb = 256 * 256;
        if (i < na) {
            int k = i >> 8, n = i & 255;
            Ta[(size_t)n * Ka + k] = f2bf(Wa[i]);
        } else if (i < na + nb) {
            int j = i - na; int k = j >> 8, n = j & 255;
            Tb[(size_t)n * 256 + k] = f2bf(Wb[j]);
        } else if (i < na + 2 * nb) {
            int j = i - na - nb; int k = j >> 8, n = j & 255;
            Tc[(size_t)n * 256 + k] = f2bf(Wc[j]);
        }
    } else {
        int i = (b - CB - TB) * 256 + threadIdx.x;
        if (i < n4) {
            float4 v = ((const float4*)x)[i];
            ushort4 o;
            o.x = f2bf(v.x); o.y = f2bf(v.y); o.z = f2bf(v.z); o.w = f2bf(v.w);
            ((ushort4*)xb)[i] = o;
        }
    }
}

// ---------------- CSR scan (2-dispatch: block sums, then scatter w/ inline prefix) ----------------

__global__ __launch_bounds__(256) void block_sum_kernel(const int* __restrict__ cnt,
                                                        int* __restrict__ bsums, int n) {
    int tid = threadIdx.x;
    int i = blockIdx.x * 256 + tid;
    int v = (i < n) ? cnt[i] : 0;
    #pragma unroll
    for (int off = 32; off > 0; off >>= 1) v += __shfl_down(v, off);
    __shared__ int ws[4];
    if ((tid & 63) == 0) ws[tid >> 6] = v;
    __syncthreads();
    if (tid == 0) bsums[blockIdx.x] = ws[0] + ws[1] + ws[2] + ws[3];
}

// computes its own block prefix: sum of bsums[k < blockIdx.x] (nb <= 256)
__global__ __launch_bounds__(256) void scatter_scan_kernel(const int* __restrict__ cnt,
                                                           const int* __restrict__ bsums,
                                                           int* __restrict__ offsets,
                                                           int* __restrict__ cursor,
                                                           float* __restrict__ dinv,
                                                           int n, int nb) {
    int tid = threadIdx.x;
    int lane = tid & 63, wid = tid >> 6;
    __shared__ int ws[4], wp[4];

    // block prefix: masked reduce of bsums
    int bv = (tid < nb && tid < (int)blockIdx.x) ? bsums[tid] : 0;
    int br = bv;
    #pragma unroll
    for (int off = 32; off > 0; off >>= 1) br += __shfl_down(br, off);
    if (lane == 0) wp[wid] = br;

    int i = blockIdx.x * 256 + tid;
    int v = (i < n) ? cnt[i] : 0;
    int s = v;
    #pragma unroll
    for (int off = 1; off < 64; off <<= 1) {
        int t = __shfl_up(s, off);
        if (lane >= off) s += t;
    }
    if (lane == 63) ws[wid] = s;
    __syncthreads();
    int wo = 0;
    #pragma unroll
    for (int k = 0; k < 4; ++k) wo += (k < wid) ? ws[k] : 0;
    int bpref = wp[0] + wp[1] + wp[2] + wp[3];
    int excl = bpref + wo + s - v;
    if (i <= n) { offsets[i] = excl; }
    if (i < n) {
        cursor[i] = excl;
        dinv[i] = rsqrtf((float)v + 1.0f);
    }
}

__global__ void fill_kernel(const int* __restrict__ src, const int* __restrict__ dst,
                            int* __restrict__ cursor, int* __restrict__ csr, int e) {
    int i = blockIdx.x * blockDim.x + threadIdx.x;
    if (i < e) {
        int p = atomicAdd(&cursor[dst[i]], 1);
        csr[p] = src[i];
    }
}

// ---------------- bf16 MFMA GEMM: C[M,256] = A[M,K] @ W[K,256], BK=64 ----------------
// MODE 0: +bias[col]   MODE 1: *dinv[row]

template <int MODE>
__global__ __launch_bounds__(256) void gemm_bf16(const unsigned short* __restrict__ A,
                                                 const unsigned short* __restrict__ Wt,
                                                 const float* __restrict__ aux,
                                                 unsigned short* __restrict__ C,
                                                 int M, int K) {
    __shared__ unsigned short As[128 * 64];   // [row][k] 16 KB
    __shared__ unsigned short Bs[128 * 64];   // [col][k] 16 KB
    const int tid  = threadIdx.x;
    const int lane = tid & 63;
    const int w    = tid >> 6;
    const int wr   = w >> 1, wc = w & 1;
    const int row0 = blockIdx.x * 128;
    const int col0 = blockIdx.y * 128;
    const int mlane = lane & 15, quad = lane >> 4;

    f32x4 acc[4][4];
    #pragma unroll
    for (int i = 0; i < 4; ++i)
        #pragma unroll
        for (int j = 0; j < 4; ++j) acc[i][j] = f32x4{0.f, 0.f, 0.f, 0.f};

    const unsigned short* gA[4]; const unsigned short* gB[4];
    unsigned short* lA[4]; unsigned short* lB[4];
    #pragma unroll
    for (int p = 0; p < 4; ++p) {
        int cid = (p * 4 + w) * 64 + lane;
        int row = cid >> 3, slot = cid & 7;
        int rowA = row0 + row; if (rowA >= M) rowA = M - 1;
        gA[p] = A + (size_t)rowA * K + slot * 8;
        gB[p] = Wt + (size_t)(col0 + row) * K + slot * 8;
        lA[p] = &As[((p * 4 + w) * 64) * 8];
        lB[p] = &Bs[((p * 4 + w) * 64) * 8];
    }

    for (int k0 = 0; k0 < K; k0 += 64) {
        #pragma unroll
        for (int p = 0; p < 4; ++p) GL2LDS16(gA[p] + k0, lA[p]);
        #pragma unroll
        for (int p = 0; p < 4; ++p) GL2LDS16(gB[p] + k0, lB[p]);
        __syncthreads();
        #pragma unroll
        for (int ks = 0; ks < 2; ++ks) {
            bf16x8 af[4], bfv[4];
            #pragma unroll
            for (int i = 0; i < 4; ++i)
                af[i] = *(const bf16x8*)&As[(wr * 64 + i * 16 + mlane) * 64 + ks * 32 + quad * 8];
            #pragma unroll
            for (int j = 0; j < 4; ++j)
                bfv[j] = *(const bf16x8*)&Bs[(wc * 64 + j * 16 + mlane) * 64 + ks * 32 + quad * 8];
            #pragma unroll
            for (int i = 0; i < 4; ++i)
                #pragma unroll
                for (int j = 0; j < 4; ++j)
                    acc[i][j] = __builtin_amdgcn_mfma_f32_16x16x32_bf16(af[i], bfv[j], acc[i][j], 0, 0, 0);
        }
        __syncthreads();
    }

    float bj[4];
    if (MODE == 0) {
        #pragma unroll
        for (int j = 0; j < 4; ++j) bj[j] = aux[col0 + wc * 64 + j * 16 + mlane];
    }
    #pragma unroll
    for (int i = 0; i < 4; ++i) {
        #pragma unroll
        for (int r = 0; r < 4; ++r) {
            int grow = row0 + wr * 64 + i * 16 + quad * 4 + r;
            if (grow < M) {
                float d = (MODE == 1) ? aux[grow] : 0.f;
                #pragma unroll
                for (int j = 0; j < 4; ++j) {
                    int gcol = col0 + wc * 64 + j * 16 + mlane;
                    float v = acc[i][j][r];
                    v = (MODE == 0) ? (v + bj[j]) : (v * d);
                    C[(size_t)grow * 256 + gcol] = f2bf(v);
                }
            }
        }
    }
}

// ---------------- aggregation: index broadcast + 8-deep gather MLP (round-6 known-good) ----------------

__global__ __launch_bounds__(256) void agg_kernel(const unsigned short* __restrict__ hs,
                                                  const int* __restrict__ offsets,
                                                  const int* __restrict__ csr,
                                                  const float* __restrict__ dinv,
                                                  const float* __restrict__ bias,
                                                  unsigned short* __restrict__ out, int n) {
    int node = blockIdx.x * 4 + (threadIdx.x >> 6);
    if (node >= n) return;
    int lane = threadIdx.x & 63;
    const ushort4* hs4 = (const ushort4*)hs;
    int beg = offsets[node], end = offsets[node + 1];
    ushort4 sv = hs4[(size_t)node * 64 + lane];
    float a0 = bf2f(sv.x), a1 = bf2f(sv.y), a2 = bf2f(sv.z), a3 = bf2f(sv.w);
    float c0 = 0.f, c1 = 0.f, c2 = 0.f, c3 = 0.f;

    int e = beg;
    while (e < end) {
        int cnt = end - e; if (cnt > 64) cnt = 64;
        int myi = (lane < cnt) ? csr[e + lane] : 0;
        int j = 0;
        for (; j + 8 <= cnt; j += 8) {
            int s0 = __shfl(myi, j + 0), s1 = __shfl(myi, j + 1);
            int s2 = __shfl(myi, j + 2), s3 = __shfl(myi, j + 3);
            int s4 = __shfl(myi, j + 4), s5 = __shfl(myi, j + 5);
            int s6 = __shfl(myi, j + 6), s7 = __shfl(myi, j + 7);
            ushort4 v0 = hs4[(size_t)s0 * 64 + lane];
            ushort4 v1 = hs4[(size_t)s1 * 64 + lane];
            ushort4 v2 = hs4[(size_t)s2 * 64 + lane];
            ushort4 v3 = hs4[(size_t)s3 * 64 + lane];
            ushort4 v4 = hs4[(size_t)s4 * 64 + lane];
            ushort4 v5 = hs4[(size_t)s5 * 64 + lane];
            ushort4 v6 = hs4[(size_t)s6 * 64 + lane];
            ushort4 v7 = hs4[(size_t)s7 * 64 + lane];
            a0 += bf2f(v0.x) + bf2f(v1.x) + bf2f(v2.x) + bf2f(v3.x);
            a1 += bf2f(v0.y) + bf2f(v1.y) + bf2f(v2.y) + bf2f(v3.y);
            a2 += bf2f(v0.z) + bf2f(v1.z) + bf2f(v2.z) + bf2f(v3.z);
            a3 += bf2f(v0.w) + bf2f(v1.w) + bf2f(v2.w) + bf2f(v3.w);
            c0 += bf2f(v4.x) + bf2f(v5.x) + bf2f(v6.x) + bf2f(v7.x);
            c1 += bf2f(v4.y) + bf2f(v5.y) + bf2f(v6.y) + bf2f(v7.y);
            c2 += bf2f(v4.z) + bf2f(v5.z) + bf2f(v6.z) + bf2f(v7.z);
            c3 += bf2f(v4.w) + bf2f(v5.w) + bf2f(v6.w) + bf2f(v7.w);
        }
        for (; j < cnt; ++j) {
            int s = __shfl(myi, j);
            ushort4 v = hs4[(size_t)s * 64 + lane];
            a0 += bf2f(v.x); a1 += bf2f(v.y); a2 += bf2f(v.z); a3 += bf2f(v.w);
        }
        e += cnt;
    }
    a0 += c0; a1 += c1; a2 += c2; a3 += c3;

    float d = dinv[node];
    float4 b = ((const float4*)bias)[lane];
    ushort4 r;
    r.x = f2bf(fmaxf(fmaf(a0, d, b.x), 0.f));
    r.y = f2bf(fmaxf(fmaf(a1, d, b.y), 0.f));
    r.z = f2bf(fmaxf(fmaf(a2, d, b.z), 0.f));
    r.w = f2bf(fmaxf(fmaf(a3, d, b.w), 0.f));
    ((ushort4*)out)[(size_t)node * 64 + lane] = r;
}

// ---------------- pooling (known-good split) ----------------

__global__ __launch_bounds__(256) void pool_partial_kernel(const unsigned short* __restrict__ h,
                                                           const int* __restrict__ batch,
                                                           float* __restrict__ sums,
                                                           int* __restrict__ counts,
                                                           int n, int chunk) {
    int beg = blockIdx.x * chunk;
    int end = beg + chunk; if (end > n) end = n;
    if (beg >= end) return;
    int c = threadIdx.x;
    int curg = batch[beg];
    float acc = 0.f;
    int runlen = 0;
    for (int i = beg; i < end; ++i) {
        int g = batch[i];
        if (g != curg) {
            atomicAdd(&sums[(size_t)curg * 256 + c], acc);
            if (c == 0) atomicAdd(&counts[curg], runlen);
            acc = 0.f; runlen = 0; curg = g;
        }
        acc += bf2f(h[(size_t)i * 256 + c]);
        ++runlen;
    }
    atomicAdd(&sums[(size_t)curg * 256 + c], acc);
    if (c == 0) atomicAdd(&counts[curg], runlen);
}

__global__ __launch_bounds__(256) void pool_final_kernel(const float* __restrict__ sums,
                                                         const int* __restrict__ counts,
                                                         const float* __restrict__ Wout,
                                                         const float* __restrict__ bout,
                                                         float* __restrict__ out) {
    __shared__ float pl[256];
    int g = blockIdx.x;
    int c = threadIdx.x;
    int cnt = counts[g];
    pl[c] = sums[(size_t)g * 256 + c] / (float)(cnt > 0 ? cnt : 1);
    __syncthreads();
    if (c < 16) {
        float o = bout[c];
        #pragma unroll 4
        for (int k = 0; k < 256; ++k) o = fmaf(pl[k], Wout[k * 16 + c], o);
        out[g * 16 + c] = o;
    }
}

// ---------------- launch ----------------

extern "C" void kernel_launch(void* const* d_in, const int* in_sizes, int n_in,
                              void* d_out, int out_size, void* d_ws, size_t ws_size,
                              hipStream_t stream) {
    const float* x     = (const float*)d_in[0];
    const int*   ei    = (const int*)d_in[1];
    const int*   batch = (const int*)d_in[2];
    const float* W_in  = (const float*)d_in[3];
    const float* b_in  = (const float*)d_in[4];
    const float* W1    = (const float*)d_in[5];
    const float* b1    = (const float*)d_in[6];
    const float* W2    = (const float*)d_in[7];
    const float* b2    = (const float*)d_in[8];
    const float* Wout  = (const float*)d_in[9];
    const float* bout  = (const float*)d_in[10];

    const int E = in_sizes[1] / 2;
    const int N = in_sizes[2];
    const int IN_DIM = in_sizes[0] / N;   // 128
    const int G = 128;
    const int* src = ei;
    const int* dst = ei + E;

    char* ws = (char*)d_ws;
    size_t off = 0;
    auto alloc = [&](size_t bytes) { size_t p = off; off += (bytes + 255) & ~(size_t)255; return p; };
    unsigned short* bufA = (unsigned short*)(ws + alloc((size_t)N * 256 * 2));
    unsigned short* bufB = (unsigned short*)(ws + alloc((size_t)N * 256 * 2));
    unsigned short* xb   = (unsigned short*)(ws + alloc((size_t)N * IN_DIM * 2));
    unsigned short* WtIn = (unsigned short*)(ws + alloc((size_t)IN_DIM * 256 * 2));
    unsigned short* Wt1  = (unsigned short*)(ws + alloc((size_t)256 * 256 * 2));
    unsigned short* Wt2  = (unsigned short*)(ws + alloc((size_t)256 * 256 * 2));
    size_t zbeg = off;
    int*   deg_cnt = (int*)(ws + alloc((size_t)N * 4));
    float* sums    = (float*)(ws + alloc((size_t)G * 256 * 4));
    int*   counts  = (int*)(ws + alloc((size_t)G * 4));
    size_t zend = off;
    float* dinv    = (float*)(ws + alloc((size_t)N * 4));
    int*   offsets = (int*)(ws + alloc((size_t)(N + 1) * 4));
    int*   cursor  = (int*)(ws + alloc((size_t)N * 4));
    int*   csr     = (int*)(ws + alloc((size_t)E * 4));
    int*   bsums   = (int*)(ws + alloc((size_t)256 * 4));
    (void)ws_size;

    const int NB  = (N + 255) / 256;
    const int NB1 = (N + 1 + 255) / 256;
    const int CB  = (E + 255) / 256;
    const int TB  = (IN_DIM * 256 + 2 * 256 * 256 + 255) / 256;
    const int XB  = (N * IN_DIM / 4 + 255) / 256;

    hipMemsetAsync(ws + zbeg, 0, zend - zbeg, stream);
    fused_misc_kernel<<<CB + TB + XB, 256, 0, stream>>>(
        dst, deg_cnt, E, W_in, WtIn, IN_DIM, W1, Wt1, W2, Wt2,
        x, xb, N * IN_DIM / 4, CB, TB);
    block_sum_kernel<<<NB, 256, 0, stream>>>(deg_cnt, bsums, N);
    scatter_scan_kernel<<<NB1, 256, 0, stream>>>(deg_cnt, bsums, offsets, cursor, dinv, N, NB);
    fill_kernel<<<(E + 255) / 256, 256, 0, stream>>>(src, dst, cursor, csr, E);

    dim3 gg((N + 127) / 128, 2);
    gemm_bf16<0><<<gg, 256, 0, stream>>>(xb, WtIn, b_in, bufA, N, IN_DIM);
    gemm_bf16<1><<<gg, 256, 0, stream>>>(bufA, Wt1, dinv, bufB, N, 256);
    agg_kernel<<<(N + 3) / 4, 256, 0, stream>>>(bufB, offsets, csr, dinv, b1, bufA, N);
    gemm_bf16<1><<<gg, 256, 0, stream>>>(bufA, Wt2, dinv, bufB, N, 256);
    agg_kernel<<<(N + 3) / 4, 256, 0, stream>>>(bufB, offsets, csr, dinv, b2, bufA, N);

    const int PBLOCKS = 512;
    int chunk = (N + PBLOCKS - 1) / PBLOCKS;
    pool_partial_kernel<<<PBLOCKS, 256, 0, stream>>>(bufA, batch, sums, counts, N, chunk);
    pool_final_kernel<<<G, 256, 0, stream>>>(sums, counts, Wout, bout, (float*)d_out);
}